// Round 2
// baseline (700.688 us; speedup 1.0000x reference)
//
#include <hip/hip_runtime.h>
#include <hip/hip_bf16.h>

#define B_ 32
#define T_ 4096
#define F_ 512
#define H_ 512

typedef float floatx4 __attribute__((ext_vector_type(4)));
typedef short short8 __attribute__((ext_vector_type(8)));

__device__ __forceinline__ unsigned short f2bf16(float a) {
  unsigned ua = __float_as_uint(a);
  return (unsigned short)((ua + 0x7FFFu + ((ua >> 16) & 1u)) >> 16);
}

// tanh(x) = 1 - 2/(e^{2x}+1); graceful at +/-inf.
__device__ __forceinline__ float tanh_fast(float x) {
  float e = __expf(2.0f * x);
  return 1.0f - __fdividef(2.0f, e + 1.0f);
}

// 8x fp32 -> 8x bf16 (RNE). Scalar casts: compiler fuses pairs into
// v_cvt_pk_bf16_f32 (m240: do NOT hand-write the asm).
__device__ __forceinline__ short8 cvt8(float4 lo, float4 hi) {
  union { short8 s8; __hip_bfloat16 h[8]; } u;
  u.h[0] = __float2bfloat16(lo.x);
  u.h[1] = __float2bfloat16(lo.y);
  u.h[2] = __float2bfloat16(lo.z);
  u.h[3] = __float2bfloat16(lo.w);
  u.h[4] = __float2bfloat16(hi.x);
  u.h[5] = __float2bfloat16(hi.y);
  u.h[6] = __float2bfloat16(hi.z);
  u.h[7] = __float2bfloat16(hi.w);
  return u.s8;
}

// ---- merged prep: W1 transpose->bf16  +  w2d = dec @ W2 (one dispatch) ----
// blocks [0,256): 32x32 transpose tiles of W1 -> W1T bf16
// blocks [256,272): w2d[b][h] over 16384 (b,h) pairs
__global__ __launch_bounds__(1024) void prep_all(const float* __restrict__ W1,
                                                 unsigned short* __restrict__ W1T,
                                                 const float* __restrict__ dec,
                                                 const float* __restrict__ W2,
                                                 float* __restrict__ w2d) {
  __shared__ float tile[32][33];
  if (blockIdx.x < 256) {
    const int tx = threadIdx.x & 31, ty = threadIdx.x >> 5;
    const int bx = blockIdx.x & 15, by = blockIdx.x >> 4;
    const int f = by * 32 + ty;
    const int h = bx * 32 + tx;
    tile[ty][tx] = W1[f * H_ + h];
    __syncthreads();
    const int ho = bx * 32 + ty;
    const int fo = by * 32 + tx;
    W1T[ho * F_ + fo] = f2bf16(tile[tx][ty]);
  } else {
    const int g = (blockIdx.x - 256) * 1024 + threadIdx.x;  // 16 blocks * 1024
    const int b = g >> 9;
    const int h = g & 511;
    float s0 = 0.f, s1 = 0.f, s2 = 0.f, s3 = 0.f;
    for (int f = 0; f < F_; f += 4) {
      s0 += dec[b * F_ + f + 0] * W2[(f + 0) * H_ + h];
      s1 += dec[b * F_ + f + 1] * W2[(f + 1) * H_ + h];
      s2 += dec[b * F_ + f + 2] * W2[(f + 2) * H_ + h];
      s3 += dec[b * F_ + f + 3] * W2[(f + 3) * H_ + h];
    }
    w2d[b * H_ + h] = (s0 + s1) + (s2 + s3);
  }
}

// ---- main: fused (enc@W1) -> tanh(+w2d) -> .V row-reduce -> atomic scores ----
// Design C: NO LDS, NO barriers. Each wave loads its MFMA fragments directly
// global->VGPR (A: 16 rows x 128B contiguous lines per fragment-pair; B: W1T
// is L2-resident 512KB), converts fp32->bf16 via cvt_pk, depth-2 register
// double-buffer. Waves fully independent; compiler emits counted vmcnt waits.
// XCD-swizzled grid: xcd = bid&7; i = bid>>3; n_blk = i&3; m_blk = xcd + 8*(i>>2)
__global__ __launch_bounds__(256, 2) void fused_score(
    const float* __restrict__ enc, const unsigned short* __restrict__ W1T,
    const float* __restrict__ w2d, const float* __restrict__ V,
    float* __restrict__ scores) {
  const int tid = threadIdx.x;
  const int bid = blockIdx.x;
  const int xcd = bid & 7;
  const int ii = bid >> 3;
  const int n_blk = ii & 3;
  const int m_blk = xcd + ((ii >> 2) << 3);
  const int lane = tid & 63;
  const int wave = tid >> 6;
  const int wm = wave >> 1;
  const int wn = wave & 1;
  const int quad = lane >> 4;
  const int l16 = lane & 15;

  // Per-fragment base pointers (loop-invariant; K offsets fit 13-bit imm).
  // A fragment i: row = m_blk*128 + wm*64 + i*16 + l16, k-offset quad*8 (fp32)
  // B fragment j: row = n_blk*128 + wn*64 + j*16 + l16, k-offset quad*8 (bf16)
  const float* ap[4];
  const unsigned short* bp[4];
#pragma unroll
  for (int i = 0; i < 4; i++)
    ap[i] = enc + (size_t)(m_blk * 128 + wm * 64 + i * 16 + l16) * F_ + quad * 8;
#pragma unroll
  for (int j = 0; j < 4; j++)
    bp[j] = W1T + (size_t)(n_blk * 128 + wn * 64 + j * 16 + l16) * F_ + quad * 8;

  floatx4 acc[4][4];
#pragma unroll
  for (int i = 0; i < 4; i++)
#pragma unroll
    for (int j = 0; j < 4; j++) acc[i][j] = (floatx4){0.f, 0.f, 0.f, 0.f};

// K-offset K is in elements (floats for A, shorts for B) — same index space.
#define ISSUE(RA, RB, K)                                     \
  do {                                                       \
    _Pragma("unroll") for (int i_ = 0; i_ < 4; i_++) {       \
      RA[2 * i_ + 0] = *(const float4*)(ap[i_] + (K));       \
      RA[2 * i_ + 1] = *(const float4*)(ap[i_] + (K) + 4);   \
    }                                                        \
    _Pragma("unroll") for (int j_ = 0; j_ < 4; j_++)         \
      RB[j_] = *(const short8*)(bp[j_] + (K));               \
  } while (0)

#define COMPUTE(RA, RB)                                               \
  do {                                                                \
    _Pragma("unroll") for (int i_ = 0; i_ < 4; i_++) {                \
      short8 af_ = cvt8(RA[2 * i_ + 0], RA[2 * i_ + 1]);              \
      _Pragma("unroll") for (int j_ = 0; j_ < 4; j_++)                \
        acc[i_][j_] = __builtin_amdgcn_mfma_f32_16x16x32_bf16(        \
            af_, RB[j_], acc[i_][j_], 0, 0, 0);                       \
    }                                                                 \
  } while (0)

  float4 raA[8], raB[8];
  short8 rbA[4], rbB[4];

  ISSUE(raA, rbA, 0);
  ISSUE(raB, rbB, 32);
#pragma unroll
  for (int ks = 0; ks < 16; ks += 2) {
    COMPUTE(raA, rbA);
    if (ks + 2 < 16) ISSUE(raA, rbA, (ks + 2) * 32);
    COMPUTE(raB, rbB);
    if (ks + 3 < 16) ISSUE(raB, rbB, (ks + 3) * 32);
  }
#undef ISSUE
#undef COMPUTE

  // epilogue: C/D layout col=lane&15, row=quad*4+reg (m89/m91-verified)
  const int b = m_blk >> 5;  // 32 m-tiles per batch row (T/128)
  float w2v[4], vv[4];
#pragma unroll
  for (int j = 0; j < 4; j++) {
    const int h = n_blk * 128 + wn * 64 + j * 16 + l16;
    w2v[j] = w2d[b * H_ + h];
    vv[j] = V[h];
  }
  float rs[4][4];
#pragma unroll
  for (int i = 0; i < 4; i++)
#pragma unroll
    for (int r = 0; r < 4; r++) {
      float s = 0.f;
#pragma unroll
      for (int j = 0; j < 4; j++) s += tanh_fast(acc[i][j][r] + w2v[j]) * vv[j];
      rs[i][r] = s;
    }
#pragma unroll
  for (int i = 0; i < 4; i++)
#pragma unroll
    for (int r = 0; r < 4; r++) {
      float s = rs[i][r];
      s += __shfl_xor(s, 1, 16);
      s += __shfl_xor(s, 2, 16);
      s += __shfl_xor(s, 4, 16);
      s += __shfl_xor(s, 8, 16);
      rs[i][r] = s;
    }
  if (l16 == 0) {
#pragma unroll
    for (int i = 0; i < 4; i++)
#pragma unroll
      for (int r = 0; r < 4; r++)
        atomicAdd(&scores[m_blk * 128 + wm * 64 + i * 16 + quad * 4 + r], rs[i][r]);
  }
}

// ---- softmax over T per batch row ----
__global__ __launch_bounds__(256) void softmax_rows(const float* __restrict__ scores,
                                                    float* __restrict__ out) {
  const int b = blockIdx.x;
  const int tid = threadIdx.x;
  const int wave = tid >> 6;
  __shared__ float red[4];
  float v[16];
  float mx = -1e30f;
#pragma unroll
  for (int i = 0; i < 16; i++) {
    v[i] = scores[b * T_ + i * 256 + tid];
    mx = fmaxf(mx, v[i]);
  }
#pragma unroll
  for (int o = 32; o > 0; o >>= 1) mx = fmaxf(mx, __shfl_xor(mx, o, 64));
  if ((tid & 63) == 0) red[wave] = mx;
  __syncthreads();
  mx = fmaxf(fmaxf(red[0], red[1]), fmaxf(red[2], red[3]));
  __syncthreads();
  float sum = 0.f;
#pragma unroll
  for (int i = 0; i < 16; i++) {
    v[i] = __expf(v[i] - mx);
    sum += v[i];
  }
#pragma unroll
  for (int o = 32; o > 0; o >>= 1) sum += __shfl_xor(sum, o, 64);
  if ((tid & 63) == 0) red[wave] = sum;
  __syncthreads();
  sum = (red[0] + red[1]) + (red[2] + red[3]);
  const float inv = 1.0f / sum;
#pragma unroll
  for (int i = 0; i < 16; i++) out[b * T_ + i * 256 + tid] = v[i] * inv;
}

extern "C" void kernel_launch(void* const* d_in, const int* in_sizes, int n_in,
                              void* d_out, int out_size, void* d_ws, size_t ws_size,
                              hipStream_t stream) {
  const float* enc = (const float*)d_in[0];  // [B,T,F]
  const float* dec = (const float*)d_in[1];  // [B,F]
  const float* W1 = (const float*)d_in[2];   // [F,H]
  const float* W2 = (const float*)d_in[3];   // [F,H]
  const float* V = (const float*)d_in[4];    // [H,1]
  float* out = (float*)d_out;                // [B,T]

  char* ws = (char*)d_ws;
  float* scores = (float*)ws;                            // 512 KB
  unsigned short* W1T = (unsigned short*)(ws + 524288);  // 512 KB
  float* w2d = (float*)(ws + 1048576);                   // 64 KB

  (void)in_sizes; (void)n_in; (void)out_size; (void)ws_size;

  hipMemsetAsync(scores, 0, B_ * T_ * sizeof(float), stream);
  prep_all<<<dim3(272), dim3(1024), 0, stream>>>(W1, W1T, dec, W2, w2d);
  fused_score<<<dim3(4096), dim3(256), 0, stream>>>(enc, W1T, w2d, V, scores);
  softmax_rows<<<dim3(32), dim3(256), 0, stream>>>(scores, out);
}

// Round 3
// 478.201 us; speedup vs baseline: 1.4653x; 1.4653x over previous
//
#include <hip/hip_runtime.h>
#include <hip/hip_bf16.h>

#define B_ 32
#define T_ 4096
#define F_ 512
#define H_ 512

typedef float floatx4 __attribute__((ext_vector_type(4)));
typedef short short8 __attribute__((ext_vector_type(8)));

__device__ __forceinline__ unsigned short f2bf16(float a) {
  unsigned ua = __float_as_uint(a);
  return (unsigned short)((ua + 0x7FFFu + ((ua >> 16) & 1u)) >> 16);
}

// tanh(x) = 1 - 2/(e^{2x}+1); graceful at +/-inf.
__device__ __forceinline__ float tanh_fast(float x) {
  float e = __expf(2.0f * x);
  return 1.0f - __fdividef(2.0f, e + 1.0f);
}

// 8x fp32 -> 8x bf16 (RNE). Scalar casts: compiler fuses pairs into
// v_cvt_pk_bf16_f32 (m240: do NOT hand-write the asm). Replaces the manual
// bit-twiddle pack (~6 VALU/pair) that made round-0 VALU-bound (38% busy).
__device__ __forceinline__ short8 cvt8(float4 lo, float4 hi) {
  union { short8 s8; __hip_bfloat16 h[8]; } u;
  u.h[0] = __float2bfloat16(lo.x);
  u.h[1] = __float2bfloat16(lo.y);
  u.h[2] = __float2bfloat16(lo.z);
  u.h[3] = __float2bfloat16(lo.w);
  u.h[4] = __float2bfloat16(hi.x);
  u.h[5] = __float2bfloat16(hi.y);
  u.h[6] = __float2bfloat16(hi.z);
  u.h[7] = __float2bfloat16(hi.w);
  return u.s8;
}

// ---- merged prep: W1 transpose->bf16  +  w2d = dec @ W2 (one dispatch) ----
__global__ __launch_bounds__(1024) void prep_all(const float* __restrict__ W1,
                                                 unsigned short* __restrict__ W1T,
                                                 const float* __restrict__ dec,
                                                 const float* __restrict__ W2,
                                                 float* __restrict__ w2d) {
  __shared__ float tile[32][33];
  if (blockIdx.x < 256) {
    const int tx = threadIdx.x & 31, ty = threadIdx.x >> 5;
    const int bx = blockIdx.x & 15, by = blockIdx.x >> 4;
    const int f = by * 32 + ty;
    const int h = bx * 32 + tx;
    tile[ty][tx] = W1[f * H_ + h];
    __syncthreads();
    const int ho = bx * 32 + ty;
    const int fo = by * 32 + tx;
    W1T[ho * F_ + fo] = f2bf16(tile[tx][ty]);
  } else {
    const int g = (blockIdx.x - 256) * 1024 + threadIdx.x;  // 16 blocks * 1024
    const int b = g >> 9;
    const int h = g & 511;
    float s0 = 0.f, s1 = 0.f, s2 = 0.f, s3 = 0.f;
    for (int f = 0; f < F_; f += 4) {
      s0 += dec[b * F_ + f + 0] * W2[(f + 0) * H_ + h];
      s1 += dec[b * F_ + f + 1] * W2[(f + 1) * H_ + h];
      s2 += dec[b * F_ + f + 2] * W2[(f + 2) * H_ + h];
      s3 += dec[b * F_ + f + 3] * W2[(f + 3) * H_ + h];
    }
    w2d[b * H_ + h] = (s0 + s1) + (s2 + s3);
  }
}

// ---- main: fused (enc@W1) -> tanh(+w2d) -> .V row-reduce -> atomic scores ----
// Round-0 verified structure (LDS double-buffer, 1 barrier/K-step, B via
// global_load_lds with XOR source swizzle). Round-3 deltas vs round-0:
//   (1) A-pack via v_cvt_pk_bf16_f32 (cvt8) instead of manual bit-ops
//   (2) __launch_bounds__(256,4): 4 blocks/CU (LDS 36KB*4=144KB<=160KB)
// NOTE (round-2 lesson): register-only prefetch does NOT survive compilation
// (scheduler sinks loads to uses, VGPR collapsed to 72, 2x slower). LDS
// staging is load-bearing here.
// XCD-swizzled grid: xcd = bid&7; i = bid>>3; n_blk = i&3; m_blk = xcd + 8*(i>>2)
__global__ __launch_bounds__(256, 4) void fused_score(
    const float* __restrict__ enc, const unsigned short* __restrict__ W1T,
    const float* __restrict__ w2d, const float* __restrict__ V,
    float* __restrict__ scores) {
  // As padded to 40 shorts/row (80B): fragment reads conflict-free (80B stride
  // spreads 8 consecutive l16 rows over all 8 16B-slots mod 128B).
  // Bs must stay lane-linear for global_load_lds -> XOR k-chunk swizzle instead.
  __shared__ __align__(16) unsigned short As[2][128 * 40];
  __shared__ __align__(16) unsigned short Bs[2][128 * 32];

  const int tid = threadIdx.x;
  const int bid = blockIdx.x;
  const int xcd = bid & 7;
  const int ii = bid >> 3;
  const int n_blk = ii & 3;
  const int m_blk = xcd + ((ii >> 2) << 3);
  const int lane = tid & 63;
  const int wave = tid >> 6;
  const int wm = wave >> 1;
  const int wn = wave & 1;
  const int quad = lane >> 4;
  const int l16 = lane & 15;

  // A staging: thread covers 8 consecutive floats in rows {arow, arow+64}
  const int arow = tid >> 2;       // 0..63
  const int acol = (tid & 3) * 8;  // float offset within 32-wide k-chunk
  const float* aptr = enc + (size_t)(m_blk * 128 + arow) * F_ + acol;

  // B staging via global_load_lds: dst is wave-uniform base + lane*16B.
  // Source XOR-swizzled so LDS slot (n, c) holds k-chunk c ^ (n&3).
  const int nb0 = wave * 32;
  const int bl_n = lane >> 2;
  const int bl_c = (lane & 3) ^ (bl_n & 3);
  const unsigned short* bsrc0 =
      W1T + (size_t)(n_blk * 128 + nb0 + bl_n) * F_ + bl_c * 8;
  const unsigned short* bsrc1 = bsrc0 + 16 * F_;

  floatx4 acc[4][4];
#pragma unroll
  for (int i = 0; i < 4; i++)
#pragma unroll
    for (int j = 0; j < 4; j++) acc[i][j] = (floatx4){0.f, 0.f, 0.f, 0.f};

  float4 a_pre[4];

  // ---- prologue: stage k-chunk 0 into buffer 0 ----
#pragma unroll
  for (int rr = 0; rr < 2; ++rr) {
    a_pre[rr * 2 + 0] = *(const float4*)(aptr + rr * 64 * F_ + 0);
    a_pre[rr * 2 + 1] = *(const float4*)(aptr + rr * 64 * F_ + 4);
  }
#pragma unroll
  for (int rr = 0; rr < 2; ++rr) {
    short8 pk = cvt8(a_pre[rr * 2 + 0], a_pre[rr * 2 + 1]);
    *(short8*)&As[0][(arow + rr * 64) * 40 + acol] = pk;
  }
  {
    __builtin_amdgcn_global_load_lds(
        (const __attribute__((address_space(1))) void*)bsrc0,
        (__attribute__((address_space(3))) void*)&Bs[0][nb0 * 32], 16, 0, 0);
    __builtin_amdgcn_global_load_lds(
        (const __attribute__((address_space(1))) void*)bsrc1,
        (__attribute__((address_space(3))) void*)&Bs[0][(nb0 + 16) * 32], 16, 0, 0);
  }
  __syncthreads();

  // ---- main K loop: single barrier per step, double-buffered ----
  for (int ks = 0; ks < 16; ++ks) {
    const int cur = ks & 1;
    const int nxt = cur ^ 1;

    if (ks < 15) {
      const int k1 = (ks + 1) * 32;
      // issue next-step VMEM early: in flight across the whole MFMA block
#pragma unroll
      for (int rr = 0; rr < 2; ++rr) {
        a_pre[rr * 2 + 0] = *(const float4*)(aptr + rr * 64 * F_ + k1);
        a_pre[rr * 2 + 1] = *(const float4*)(aptr + rr * 64 * F_ + k1 + 4);
      }
      __builtin_amdgcn_global_load_lds(
          (const __attribute__((address_space(1))) void*)(bsrc0 + k1),
          (__attribute__((address_space(3))) void*)&Bs[nxt][nb0 * 32], 16, 0, 0);
      __builtin_amdgcn_global_load_lds(
          (const __attribute__((address_space(1))) void*)(bsrc1 + k1),
          (__attribute__((address_space(3))) void*)&Bs[nxt][(nb0 + 16) * 32], 16, 0, 0);
    }

    short8 af[4], bfr[4];
#pragma unroll
    for (int i = 0; i < 4; i++)
      af[i] = *(const short8*)&As[cur][(wm * 64 + i * 16 + l16) * 40 + quad * 8];
#pragma unroll
    for (int j = 0; j < 4; j++)
      bfr[j] = *(const short8*)&Bs[cur][(wn * 64 + j * 16 + l16) * 32 +
                                        ((quad ^ (l16 & 3)) * 8)];
#pragma unroll
    for (int i = 0; i < 4; i++)
#pragma unroll
      for (int j = 0; j < 4; j++)
        acc[i][j] = __builtin_amdgcn_mfma_f32_16x16x32_bf16(af[i], bfr[j], acc[i][j], 0, 0, 0);

    if (ks < 15) {
#pragma unroll
      for (int rr = 0; rr < 2; ++rr) {
        short8 pk = cvt8(a_pre[rr * 2 + 0], a_pre[rr * 2 + 1]);
        *(short8*)&As[nxt][(arow + rr * 64) * 40 + acol] = pk;
      }
    }
    __syncthreads();
  }

  // epilogue: C/D layout col=lane&15, row=quad*4+reg (m89/m91-verified)
  const int b = m_blk >> 5;  // 32 m-tiles per batch row (T/128)
  float w2v[4], vv[4];
#pragma unroll
  for (int j = 0; j < 4; j++) {
    const int h = n_blk * 128 + wn * 64 + j * 16 + l16;
    w2v[j] = w2d[b * H_ + h];
    vv[j] = V[h];
  }
  float rs[4][4];
#pragma unroll
  for (int i = 0; i < 4; i++)
#pragma unroll
    for (int r = 0; r < 4; r++) {
      float s = 0.f;
#pragma unroll
      for (int j = 0; j < 4; j++) s += tanh_fast(acc[i][j][r] + w2v[j]) * vv[j];
      rs[i][r] = s;
    }
#pragma unroll
  for (int i = 0; i < 4; i++)
#pragma unroll
    for (int r = 0; r < 4; r++) {
      float s = rs[i][r];
      s += __shfl_xor(s, 1, 16);
      s += __shfl_xor(s, 2, 16);
      s += __shfl_xor(s, 4, 16);
      s += __shfl_xor(s, 8, 16);
      rs[i][r] = s;
    }
  if (l16 == 0) {
#pragma unroll
    for (int i = 0; i < 4; i++)
#pragma unroll
      for (int r = 0; r < 4; r++)
        atomicAdd(&scores[m_blk * 128 + wm * 64 + i * 16 + quad * 4 + r], rs[i][r]);
  }
}

// ---- softmax over T per batch row ----
__global__ __launch_bounds__(256) void softmax_rows(const float* __restrict__ scores,
                                                    float* __restrict__ out) {
  const int b = blockIdx.x;
  const int tid = threadIdx.x;
  const int wave = tid >> 6;
  __shared__ float red[4];
  float v[16];
  float mx = -1e30f;
#pragma unroll
  for (int i = 0; i < 16; i++) {
    v[i] = scores[b * T_ + i * 256 + tid];
    mx = fmaxf(mx, v[i]);
  }
#pragma unroll
  for (int o = 32; o > 0; o >>= 1) mx = fmaxf(mx, __shfl_xor(mx, o, 64));
  if ((tid & 63) == 0) red[wave] = mx;
  __syncthreads();
  mx = fmaxf(fmaxf(red[0], red[1]), fmaxf(red[2], red[3]));
  __syncthreads();
  float sum = 0.f;
#pragma unroll
  for (int i = 0; i < 16; i++) {
    v[i] = __expf(v[i] - mx);
    sum += v[i];
  }
#pragma unroll
  for (int o = 32; o > 0; o >>= 1) sum += __shfl_xor(sum, o, 64);
  if ((tid & 63) == 0) red[wave] = sum;
  __syncthreads();
  sum = (red[0] + red[1]) + (red[2] + red[3]);
  const float inv = 1.0f / sum;
#pragma unroll
  for (int i = 0; i < 16; i++) out[b * T_ + i * 256 + tid] = v[i] * inv;
}

extern "C" void kernel_launch(void* const* d_in, const int* in_sizes, int n_in,
                              void* d_out, int out_size, void* d_ws, size_t ws_size,
                              hipStream_t stream) {
  const float* enc = (const float*)d_in[0];  // [B,T,F]
  const float* dec = (const float*)d_in[1];  // [B,F]
  const float* W1 = (const float*)d_in[2];   // [F,H]
  const float* W2 = (const float*)d_in[3];   // [F,H]
  const float* V = (const float*)d_in[4];    // [H,1]
  float* out = (float*)d_out;                // [B,T]

  char* ws = (char*)d_ws;
  float* scores = (float*)ws;                            // 512 KB
  unsigned short* W1T = (unsigned short*)(ws + 524288);  // 512 KB
  float* w2d = (float*)(ws + 1048576);                   // 64 KB

  (void)in_sizes; (void)n_in; (void)out_size; (void)ws_size;

  hipMemsetAsync(scores, 0, B_ * T_ * sizeof(float), stream);
  prep_all<<<dim3(272), dim3(1024), 0, stream>>>(W1, W1T, dec, W2, w2d);
  fused_score<<<dim3(4096), dim3(256), 0, stream>>>(enc, W1T, w2d, V, scores);
  softmax_rows<<<dim3(32), dim3(256), 0, stream>>>(scores, out);
}